// Round 1
// baseline (692.929 us; speedup 1.0000x reference)
//
#include <hip/hip_runtime.h>

// Decoder: N=4096 independent LSTM sequences (K=16 z-samples x B=256), H=64, T=50,
// GMM head (GC=16, PD=2), output (K,B) fp32 sums of per-step log probs.
//
// Strategy: persistent kernel, 256 blocks x 16 samples, 256 threads.
//  - gates_const = zx@Wih[:,:320].T + bih + bhh precomputed in-block (registers)
//  - per step: gates = gates_const + d_t . Wih[:,320:322].T + h @ Whh.T  (Whh rows in regs)
//  - LDS exchange for gate->state update, h kept in LDS (padded stride 68)
//  - fused projection + GMM: thread (s,g) computes the 6 dots for component g,
//    logsumexp via 16-lane shfl butterfly, accumulate over t, write out once.

#define T_ 50
#define SPB 16        // samples per block
#define ZXD 320
#define LSTM_IN 322

__device__ __forceinline__ float sigf(float x)  { return 1.0f / (1.0f + __expf(-x)); }
__device__ __forceinline__ float tanh_(float x) { return 1.0f - 2.0f / (__expf(2.0f * x) + 1.0f); }

__launch_bounds__(256, 1)
__global__ void decoder_kernel(
    const float* __restrict__ x,       const float* __restrict__ z,
    const float* __restrict__ inp_seqs,const float* __restrict__ pred_seqs,
    const float* __restrict__ Wh0,     const float* __restrict__ bh0,
    const float* __restrict__ Wc0,     const float* __restrict__ bc0,
    const float* __restrict__ Wih,     const float* __restrict__ Whh,
    const float* __restrict__ bih,     const float* __restrict__ bhh,
    const float* __restrict__ Wpi,     const float* __restrict__ bpi,
    const float* __restrict__ Wmu,     const float* __restrict__ bmu,
    const float* __restrict__ Wls,     const float* __restrict__ bls,
    const float* __restrict__ Wcorr,   const float* __restrict__ bcorr,
    float* __restrict__ out)
{
    __shared__ __align__(16) float smem[96*68 + 16*68 + 6144];
    float* WP  = smem;                    // 96 x 68 (proj weights, padded)
    float* HL  = smem + 96*68;            // 16 x 68 (h state, padded)
    float* RG  = smem + 96*68 + 16*68;    // overlaid region
    float* ZXL = RG;                      // prologue: 16 x 320
    float* C0X = RG + 5120;               // prologue: 16 x 64 c0 exchange
    float* GL  = RG;                      // main: 16 x 256 gates
    float* FUT = RG + 4096;               // main: 50 x 16 x 2 targets
    float* PRS = RG + 5696;               // main: 16 x 2 present

    const int j   = threadIdx.x;
    const int blk = blockIdx.x;

    // ---- load projection weights into LDS (rows: 0..15 pi, 16..47 mu, 48..79 ls, 80..95 corr)
    for (int e = j; e < 96*64; e += 256) {
        int r = e >> 6, k = e & 63;
        float v;
        if      (r < 16) v = Wpi [r*64 + k];
        else if (r < 48) v = Wmu [(r-16)*64 + k];
        else if (r < 80) v = Wls [(r-48)*64 + k];
        else             v = Wcorr[(r-80)*64 + k];
        WP[r*68 + k] = v;
    }
    // ---- build zx in LDS
    for (int e = j; e < SPB*ZXD; e += 256) {
        int s = e / ZXD, k = e - s*ZXD;
        int n = blk*SPB + s; int kk = n >> 8; int b = n & 255;
        ZXL[s*ZXD + k] = (k < 64) ? z[(kk*256 + b)*64 + k] : x[b*256 + (k - 64)];
    }
    __syncthreads();

    // ---- phase A: gates_const row j for all 16 samples (K=320, k-tiled regs)
    float gc[SPB];
    {
        float bj = bih[j] + bhh[j];
        #pragma unroll
        for (int s = 0; s < SPB; ++s) gc[s] = bj;
        const float* wrow = Wih + j*LSTM_IN;
        for (int kt = 0; kt < 5; ++kt) {
            float w[64];
            #pragma unroll
            for (int q = 0; q < 32; ++q) {
                float2 t2 = *reinterpret_cast<const float2*>(wrow + kt*64 + 2*q);
                w[2*q] = t2.x; w[2*q+1] = t2.y;
            }
            #pragma unroll
            for (int s = 0; s < SPB; ++s) {
                #pragma unroll
                for (int q = 0; q < 16; ++q) {
                    float4 zv = *reinterpret_cast<const float4*>(&ZXL[s*ZXD + kt*64 + 4*q]);
                    gc[s] = fmaf(zv.x, w[4*q  ], gc[s]);
                    gc[s] = fmaf(zv.y, w[4*q+1], gc[s]);
                    gc[s] = fmaf(zv.z, w[4*q+2], gc[s]);
                    gc[s] = fmaf(zv.w, w[4*q+3], gc[s]);
                }
            }
        }
    }
    const float wd0 = Wih[j*LSTM_IN + 320], wd1 = Wih[j*LSTM_IN + 321];

    // ---- phase B: h0 / c0  (thread = (row r in [0,128), sample-half))
    {
        int r = j & 127, half = j >> 7, u = r & 63;
        const float* wrow = (r < 64) ? (Wh0 + u*ZXD) : (Wc0 + u*ZXD);
        float bias = (r < 64) ? bh0[u] : bc0[u];
        float accB[8];
        #pragma unroll
        for (int i = 0; i < 8; ++i) accB[i] = bias;
        for (int kt = 0; kt < 5; ++kt) {
            float w[64];
            #pragma unroll
            for (int q = 0; q < 16; ++q) {
                float4 t4 = *reinterpret_cast<const float4*>(wrow + kt*64 + 4*q);
                w[4*q]=t4.x; w[4*q+1]=t4.y; w[4*q+2]=t4.z; w[4*q+3]=t4.w;
            }
            #pragma unroll
            for (int i = 0; i < 8; ++i) {
                int s = half*8 + i;
                #pragma unroll
                for (int q = 0; q < 16; ++q) {
                    float4 zv = *reinterpret_cast<const float4*>(&ZXL[s*ZXD + kt*64 + 4*q]);
                    accB[i] = fmaf(zv.x, w[4*q  ], accB[i]);
                    accB[i] = fmaf(zv.y, w[4*q+1], accB[i]);
                    accB[i] = fmaf(zv.z, w[4*q+2], accB[i]);
                    accB[i] = fmaf(zv.w, w[4*q+3], accB[i]);
                }
            }
        }
        #pragma unroll
        for (int i = 0; i < 8; ++i) {
            int s = half*8 + i;
            if (r < 64) HL[s*68 + u]  = accB[i];
            else        C0X[s*64 + u] = accB[i];
        }
    }
    __syncthreads();

    // ---- pick up c0 into per-thread registers (phase-2 mapping)
    float c4[4];
    {
        int u = j & 63, sg = j >> 6;
        #pragma unroll
        for (int i = 0; i < 4; ++i) c4[i] = C0X[(i*4 + sg)*64 + u];
    }
    __syncthreads();   // done with ZXL/C0X; region becomes GL/FUT/PRS

    // ---- load targets (decode inputs + gmm values)
    for (int e = j; e < T_*SPB; e += 256) {
        int t = e >> 4, s = e & 15;
        int b = (blk*SPB + s) & 255;
        float2 v = *reinterpret_cast<const float2*>(pred_seqs + b*1200 + t*24 + 20);
        FUT[t*32 + s*2] = v.x; FUT[t*32 + s*2 + 1] = v.y;
    }
    if (j < SPB) {
        int b = (blk*SPB + j) & 255;
        float2 v = *reinterpret_cast<const float2*>(inp_seqs + b*192 + 188);
        PRS[j*2] = v.x; PRS[j*2 + 1] = v.y;
    }

    // ---- Whh row j into registers
    float whh[64];
    {
        const float* wr = Whh + j*64;
        #pragma unroll
        for (int q = 0; q < 16; ++q) {
            float4 t4 = *reinterpret_cast<const float4*>(wr + 4*q);
            whh[4*q]=t4.x; whh[4*q+1]=t4.y; whh[4*q+2]=t4.z; whh[4*q+3]=t4.w;
        }
    }

    // ---- GMM-role constants (thread = (sample s3, component g3))
    const int s3 = j >> 4, g3 = j & 15;
    const float b_pi = bpi[g3], b_m0 = bmu[2*g3], b_m1 = bmu[2*g3+1];
    const float b_l0 = bls[2*g3], b_l1 = bls[2*g3+1], b_co = bcorr[g3];
    const int r_pi = g3, r_m0 = 16+2*g3, r_m1 = 17+2*g3,
              r_l0 = 48+2*g3, r_l1 = 49+2*g3, r_co = 80+g3;
    float sum = 0.0f;

    __syncthreads();

    for (int t = 0; t < T_; ++t) {
        // ---- phase 1: gates[s][j] = gc + d.wd + h @ whh_row
        float acc[SPB];
        const float* dptr = (t == 0) ? PRS : &FUT[(t-1)*32];
        #pragma unroll
        for (int s = 0; s < SPB; ++s)
            acc[s] = fmaf(dptr[s*2], wd0, fmaf(dptr[s*2+1], wd1, gc[s]));
        #pragma unroll
        for (int q = 0; q < 16; ++q) {
            #pragma unroll
            for (int s = 0; s < SPB; ++s) {
                float4 h4 = *reinterpret_cast<const float4*>(&HL[s*68 + 4*q]);
                acc[s] = fmaf(h4.x, whh[4*q  ], acc[s]);
                acc[s] = fmaf(h4.y, whh[4*q+1], acc[s]);
                acc[s] = fmaf(h4.z, whh[4*q+2], acc[s]);
                acc[s] = fmaf(h4.w, whh[4*q+3], acc[s]);
            }
        }
        #pragma unroll
        for (int s = 0; s < SPB; ++s) GL[s*256 + j] = acc[s];
        __syncthreads();

        // ---- phase 2: LSTM cell update (thread = (unit u, sample-group sg))
        {
            int u = j & 63, sg = j >> 6;
            #pragma unroll
            for (int i = 0; i < 4; ++i) {
                int s = i*4 + sg;
                float ii = GL[s*256 + u];
                float ff = GL[s*256 + 64 + u];
                float gg = GL[s*256 + 128 + u];
                float oo = GL[s*256 + 192 + u];
                float cc = sigf(ff)*c4[i] + sigf(ii)*tanh_(gg);
                c4[i] = cc;
                HL[s*68 + u] = sigf(oo)*tanh_(cc);
            }
        }
        __syncthreads();

        // ---- phase 3: projections + GMM log-prob for (s3, g3)
        {
            float a_pi=b_pi, a_m0=b_m0, a_m1=b_m1, a_l0=b_l0, a_l1=b_l1, a_co=b_co;
            #pragma unroll
            for (int q = 0; q < 16; ++q) {
                float4 h4 = *reinterpret_cast<const float4*>(&HL[s3*68 + 4*q]);
                float4 w;
                #define DOT4(accv, rowb) \
                    w = *reinterpret_cast<const float4*>(&WP[(rowb)*68 + 4*q]); \
                    accv = fmaf(h4.x,w.x, fmaf(h4.y,w.y, fmaf(h4.z,w.z, fmaf(h4.w,w.w, accv))));
                DOT4(a_pi, r_pi) DOT4(a_m0, r_m0) DOT4(a_m1, r_m1)
                DOT4(a_l0, r_l0) DOT4(a_l1, r_l1) DOT4(a_co, r_co)
                #undef DOT4
            }
            float v0 = FUT[t*32 + s3*2], v1 = FUT[t*32 + s3*2 + 1];
            float l0 = fminf(fmaxf(a_l0, -10.0f), 10.0f);
            float l1 = fminf(fmaxf(a_l1, -10.0f), 10.0f);
            float z0 = (v0 - a_m0) * __expf(-l0);
            float z1 = (v1 - a_m1) * __expf(-l1);
            float ct = tanh_(a_co);
            float omr = 1.0f - ct*ct;
            float quad = z0*z0 + z1*z1 - 2.0f*ct*z0*z1;
            float comp = -1.8378770664093453f - (l0 + l1) - 0.5f*__logf(omr) - 0.5f*quad/omr;
            float a = a_pi + comp;
            float m1v = a, m2v = a_pi;
            #pragma unroll
            for (int off = 1; off < 16; off <<= 1) {
                m1v = fmaxf(m1v, __shfl_xor(m1v, off));
                m2v = fmaxf(m2v, __shfl_xor(m2v, off));
            }
            float e1 = __expf(a - m1v), e2 = __expf(a_pi - m2v);
            #pragma unroll
            for (int off = 1; off < 16; off <<= 1) {
                e1 += __shfl_xor(e1, off);
                e2 += __shfl_xor(e2, off);
            }
            float logp = (m1v + __logf(e1)) - (m2v + __logf(e2));
            sum += fminf(logp, 50.0f);
        }
        // no barrier needed here: next phase-1 only reads HL (stable until next
        // phase-2, which is behind next phase-1's barrier) and writes GL (all
        // phase-2 reads completed before the phase-2-end barrier above).
    }

    if (g3 == 0) out[blk*SPB + s3] = sum;
}

extern "C" void kernel_launch(void* const* d_in, const int* in_sizes, int n_in,
                              void* d_out, int out_size, void* d_ws, size_t ws_size,
                              hipStream_t stream) {
    const float* x     = (const float*)d_in[0];
    const float* z     = (const float*)d_in[1];
    const float* iseq  = (const float*)d_in[2];
    const float* pseq  = (const float*)d_in[3];
    const float* Wh0   = (const float*)d_in[4];
    const float* bh0   = (const float*)d_in[5];
    const float* Wc0   = (const float*)d_in[6];
    const float* bc0   = (const float*)d_in[7];
    const float* Wih   = (const float*)d_in[8];
    const float* Whh   = (const float*)d_in[9];
    const float* bih   = (const float*)d_in[10];
    const float* bhh   = (const float*)d_in[11];
    const float* Wpi   = (const float*)d_in[12];
    const float* bpi   = (const float*)d_in[13];
    const float* Wmu   = (const float*)d_in[14];
    const float* bmu   = (const float*)d_in[15];
    const float* Wls   = (const float*)d_in[16];
    const float* bls   = (const float*)d_in[17];
    const float* Wcorr = (const float*)d_in[18];
    const float* bcorr = (const float*)d_in[19];
    float* out = (float*)d_out;

    decoder_kernel<<<256, 256, 0, stream>>>(x, z, iseq, pseq, Wh0, bh0, Wc0, bc0,
                                            Wih, Whh, bih, bhh, Wpi, bpi, Wmu, bmu,
                                            Wls, bls, Wcorr, bcorr, out);
}

// Round 2
// 112.729 us; speedup vs baseline: 6.1469x; 6.1469x over previous
//
#include <hip/hip_runtime.h>

// Decoder: N=4096 LSTM sequences (K=16 x B=256), H=64, T=50, GMM head (GC=16, PD=2).
// MFMA rewrite: 256 blocks x 512 threads (8 waves). Per block: 16 samples.
//  - All GEMM-shaped work on v_mfma_f32_16x16x32_bf16 with hi/lo bf16 split
//    (hi*hi + hi*lo + lo*hi ~ fp32 accuracy).
//  - Whh / proj-weight B-fragments prepacked in registers (prologue), zero
//    in-loop LDS weight traffic.
//  - h stored as bf16 hi/lo in A-frag layout (ushort stride 72): one
//    ds_read_b128 per k-slice.
//  - gates_const (zx@Wih.T) and h0/c0 also via MFMA in prologue.

#define T_ 50
#define SPB 16
#define ZXS 324      // padded zx LDS stride (floats)
#define HFS 72       // h bf16 LDS stride (ushorts)
#define GLS 256
#define PLS 100

typedef __attribute__((ext_vector_type(8))) short short8;
typedef __attribute__((ext_vector_type(4))) float f32x4;

#define MFMA(a, b, c) __builtin_amdgcn_mfma_f32_16x16x32_bf16(a, b, c, 0, 0, 0)

__device__ __forceinline__ float sigf(float x)  { return 1.0f / (1.0f + __expf(-x)); }
__device__ __forceinline__ float tanh_(float x) { return 1.0f - 2.0f / (__expf(2.0f * x) + 1.0f); }

__device__ __forceinline__ void splitf(float f, unsigned short& hi, unsigned short& lo) {
    unsigned b = __float_as_uint(f);
    hi = (unsigned short)(b >> 16);
    float fh = __uint_as_float(b & 0xffff0000u);
    lo = (unsigned short)(__float_as_uint(f - fh) >> 16);
}

__device__ __forceinline__ void pack8(const float* p, short8& hi, short8& lo) {
    #pragma unroll
    for (int e = 0; e < 8; ++e) {
        unsigned short h, l;
        splitf(p[e], h, l);
        hi[e] = (short)h; lo[e] = (short)l;
    }
}

__launch_bounds__(512, 2)
__global__ void decoder_kernel(
    const float* __restrict__ x,       const float* __restrict__ z,
    const float* __restrict__ inp_seqs,const float* __restrict__ pred_seqs,
    const float* __restrict__ Wh0,     const float* __restrict__ bh0,
    const float* __restrict__ Wc0,     const float* __restrict__ bc0,
    const float* __restrict__ Wih,     const float* __restrict__ Whh,
    const float* __restrict__ bih,     const float* __restrict__ bhh,
    const float* __restrict__ Wpi,     const float* __restrict__ bpi,
    const float* __restrict__ Wmu,     const float* __restrict__ bmu,
    const float* __restrict__ Wls,     const float* __restrict__ bls,
    const float* __restrict__ Wcorr,   const float* __restrict__ bcorr,
    float* __restrict__ out)
{
    // LDS: [0,5696) ZXL(prologue, 16x324) / GL(16x256)+PL(16x100) (main)
    //      [5696,6720) C0X  [6720,7296) HFhi  [7296,7872) HFlo
    //      [7872,9472) FUT  [9472,9504) PRS
    __shared__ __align__(16) float smem[9504];
    float* ZXL = smem;
    float* GL  = smem;
    float* PL  = smem + 4096;
    float* C0X = smem + 5696;
    unsigned short* HFhi = (unsigned short*)(smem + 6720);
    unsigned short* HFlo = (unsigned short*)(smem + 7296);
    float* FUT = smem + 7872;
    float* PRS = smem + 9472;

    const int j = threadIdx.x;
    const int w = j >> 6;     // wave 0..7
    const int l = j & 63;     // lane
    const int g = l >> 4;     // k-group 0..3
    const int c = l & 15;     // col-in-tile / A-row
    const int blk = blockIdx.x;

    // ---- build ZXL, FUT, PRS
    for (int e = j; e < SPB*320; e += 512) {
        int s = e / 320, k = e - s*320;
        int n = blk*SPB + s; int kk = n >> 8; int b = n & 255;
        ZXL[s*ZXS + k] = (k < 64) ? z[(kk*256 + b)*64 + k] : x[b*256 + (k - 64)];
    }
    for (int e = j; e < T_*SPB; e += 512) {
        int t = e >> 4, s = e & 15;
        int b = (blk*SPB + s) & 255;
        float2 v = *reinterpret_cast<const float2*>(pred_seqs + b*1200 + t*24 + 20);
        FUT[t*32 + s*2] = v.x; FUT[t*32 + s*2 + 1] = v.y;
    }
    if (j < SPB) {
        int b = (blk*SPB + j) & 255;
        float2 v = *reinterpret_cast<const float2*>(inp_seqs + b*192 + 188);
        PRS[j*2] = v.x; PRS[j*2 + 1] = v.y;
    }
    __syncthreads();

    // ---- prologue MFMA: gates_const (2 tiles/wave), h0/c0 (1 tile/wave)
    const int gate0 = w*32 + c;
    const int gate1 = w*32 + 16 + c;
    const int colB  = w*16 + c;          // 0..127: h0 cols 0-63, c0 cols 64-127

    f32x4 gc0, gc1, accB;
    {
        float bA0 = bih[gate0] + bhh[gate0];
        float bA1 = bih[gate1] + bhh[gate1];
        float bB  = (w < 4) ? bh0[colB] : bc0[colB - 64];
        gc0 = (f32x4){bA0, bA0, bA0, bA0};
        gc1 = (f32x4){bA1, bA1, bA1, bA1};
        accB = (f32x4){bB, bB, bB, bB};
    }
    const float* rowA0 = Wih + gate0*322;
    const float* rowA1 = Wih + gate1*322;
    const float* rowB  = (w < 4) ? (Wh0 + colB*320) : (Wc0 + (colB - 64)*320);

    for (int ks = 0; ks < 10; ++ks) {
        int k0 = ks*32 + g*8;
        short8 ahi, alo, b0h, b0l, b1h, b1l, bbh, bbl;
        pack8(&ZXL[c*ZXS + k0], ahi, alo);
        pack8(rowA0 + k0, b0h, b0l);
        pack8(rowA1 + k0, b1h, b1l);
        pack8(rowB  + k0, bbh, bbl);
        gc0  = MFMA(ahi, b0h, gc0);  gc0  = MFMA(ahi, b0l, gc0);  gc0  = MFMA(alo, b0h, gc0);
        gc1  = MFMA(ahi, b1h, gc1);  gc1  = MFMA(ahi, b1l, gc1);  gc1  = MFMA(alo, b1h, gc1);
        accB = MFMA(ahi, bbh, accB); accB = MFMA(ahi, bbl, accB); accB = MFMA(alo, bbh, accB);
    }

    // write h0 (bf16 hi/lo frag layout) / c0 (fp32)
    if (w < 4) {
        #pragma unroll
        for (int r = 0; r < 4; ++r) {
            int s = g*4 + r;
            unsigned short hh, ll; splitf(accB[r], hh, ll);
            HFhi[s*HFS + colB] = hh; HFlo[s*HFS + colB] = ll;
        }
    } else {
        #pragma unroll
        for (int r = 0; r < 4; ++r) C0X[(g*4 + r)*64 + (colB - 64)] = accB[r];
    }

    // phase-1 d-weights, Whh B-frags (2 tiles x 2 kslices, hi/lo)
    const float wd00 = rowA0[320], wd01 = rowA0[321];
    const float wd10 = rowA1[320], wd11 = rowA1[321];
    short8 w1h00, w1l00, w1h01, w1l01, w1h10, w1l10, w1h11, w1l11;
    pack8(Whh + gate0*64 +      g*8, w1h00, w1l00);
    pack8(Whh + gate0*64 + 32 + g*8, w1h01, w1l01);
    pack8(Whh + gate1*64 +      g*8, w1h10, w1l10);
    pack8(Whh + gate1*64 + 32 + g*8, w1h11, w1l11);

    // phase-3 B-frags + bias (waves 0..5; dummy row for 6,7)
    short8 b3h0, b3l0, b3h1, b3l1;
    float bias3;
    {
        int r3 = (w < 6) ? (w*16 + c) : 0;
        const float* prow; float bb;
        if (r3 < 16)      { prow = Wpi   + r3*64;       bb = bpi[r3]; }
        else if (r3 < 48) { prow = Wmu   + (r3-16)*64;  bb = bmu[r3-16]; }
        else if (r3 < 80) { prow = Wls   + (r3-48)*64;  bb = bls[r3-48]; }
        else              { prow = Wcorr + (r3-80)*64;  bb = bcorr[r3-80]; }
        bias3 = bb;
        pack8(prow +      g*8, b3h0, b3l0);
        pack8(prow + 32 + g*8, b3h1, b3l1);
    }

    __syncthreads();   // h0/c0 visible; ZXL dead -> region becomes GL/PL

    // c-state pickup (phase-2 mapping: thread = (u, sg), samples 2*sg, 2*sg+1)
    const int u2 = j & 63, sg2 = j >> 6;
    float cst0 = C0X[(2*sg2 + 0)*64 + u2];
    float cst1 = C0X[(2*sg2 + 1)*64 + u2];

    const int s3 = j >> 4, g3 = j & 15;   // GMM role (threads < 256)
    float sum = 0.0f;

    for (int t = 0; t < T_; ++t) {
        // ---- phase 1: gates = gc + d.wd + h @ Whh.T (MFMA)
        {
            const float* dptr = (t == 0) ? PRS : &FUT[(t-1)*32];
            f32x4 a0, a1;
            #pragma unroll
            for (int r = 0; r < 4; ++r) {
                float2 dv = *reinterpret_cast<const float2*>(dptr + (g*4 + r)*2);
                a0[r] = gc0[r] + dv.x*wd00 + dv.y*wd01;
                a1[r] = gc1[r] + dv.x*wd10 + dv.y*wd11;
            }
            short8 ah0 = *reinterpret_cast<const short8*>(HFhi + c*HFS +      g*8);
            short8 al0 = *reinterpret_cast<const short8*>(HFlo + c*HFS +      g*8);
            short8 ah1 = *reinterpret_cast<const short8*>(HFhi + c*HFS + 32 + g*8);
            short8 al1 = *reinterpret_cast<const short8*>(HFlo + c*HFS + 32 + g*8);
            a0 = MFMA(ah0, w1h00, a0); a0 = MFMA(ah0, w1l00, a0); a0 = MFMA(al0, w1h00, a0);
            a0 = MFMA(ah1, w1h01, a0); a0 = MFMA(ah1, w1l01, a0); a0 = MFMA(al1, w1h01, a0);
            a1 = MFMA(ah0, w1h10, a1); a1 = MFMA(ah0, w1l10, a1); a1 = MFMA(al0, w1h10, a1);
            a1 = MFMA(ah1, w1h11, a1); a1 = MFMA(ah1, w1l11, a1); a1 = MFMA(al1, w1h11, a1);
            #pragma unroll
            for (int r = 0; r < 4; ++r) {
                GL[(g*4 + r)*GLS + gate0] = a0[r];
                GL[(g*4 + r)*GLS + gate1] = a1[r];
            }
        }
        __syncthreads();

        // ---- phase 2: LSTM cell update, write h as bf16 hi/lo frags
        {
            #pragma unroll
            for (int i = 0; i < 2; ++i) {
                int s = 2*sg2 + i;
                float gi = GL[s*GLS + u2];
                float gf = GL[s*GLS + 64  + u2];
                float gg = GL[s*GLS + 128 + u2];
                float go = GL[s*GLS + 192 + u2];
                float cp = (i == 0) ? cst0 : cst1;
                float cc = sigf(gf)*cp + sigf(gi)*tanh_(gg);
                if (i == 0) cst0 = cc; else cst1 = cc;
                float hh = sigf(go)*tanh_(cc);
                unsigned short uh, ul; splitf(hh, uh, ul);
                HFhi[s*HFS + u2] = uh; HFlo[s*HFS + u2] = ul;
            }
        }
        __syncthreads();

        // ---- phase 3: projections via MFMA (waves 0..5)
        if (w < 6) {
            short8 ah0 = *reinterpret_cast<const short8*>(HFhi + c*HFS +      g*8);
            short8 al0 = *reinterpret_cast<const short8*>(HFlo + c*HFS +      g*8);
            short8 ah1 = *reinterpret_cast<const short8*>(HFhi + c*HFS + 32 + g*8);
            short8 al1 = *reinterpret_cast<const short8*>(HFlo + c*HFS + 32 + g*8);
            f32x4 p = (f32x4){bias3, bias3, bias3, bias3};
            p = MFMA(ah0, b3h0, p); p = MFMA(ah0, b3l0, p); p = MFMA(al0, b3h0, p);
            p = MFMA(ah1, b3h1, p); p = MFMA(ah1, b3l1, p); p = MFMA(al1, b3h1, p);
            #pragma unroll
            for (int r = 0; r < 4; ++r) PL[(g*4 + r)*PLS + w*16 + c] = p[r];
        }
        __syncthreads();

        // ---- GMM log-prob (threads < 256)
        if (j < 256) {
            const float* pls = PL + s3*PLS;
            float a_pi = pls[g3];
            float a_m0 = pls[16 + 2*g3], a_m1 = pls[17 + 2*g3];
            float l0   = pls[48 + 2*g3], l1   = pls[49 + 2*g3];
            float a_co = pls[80 + g3];
            float v0 = FUT[t*32 + s3*2], v1 = FUT[t*32 + s3*2 + 1];
            l0 = fminf(fmaxf(l0, -10.0f), 10.0f);
            l1 = fminf(fmaxf(l1, -10.0f), 10.0f);
            float z0 = (v0 - a_m0) * __expf(-l0);
            float z1 = (v1 - a_m1) * __expf(-l1);
            float ct = tanh_(a_co);
            float omr = 1.0f - ct*ct;
            float quad = z0*z0 + z1*z1 - 2.0f*ct*z0*z1;
            float comp = -1.8378770664093453f - (l0 + l1) - 0.5f*__logf(omr) - 0.5f*quad/omr;
            float a = a_pi + comp;
            float m1v = a, m2v = a_pi;
            #pragma unroll
            for (int off = 1; off < 16; off <<= 1) {
                m1v = fmaxf(m1v, __shfl_xor(m1v, off));
                m2v = fmaxf(m2v, __shfl_xor(m2v, off));
            }
            float e1 = __expf(a - m1v), e2 = __expf(a_pi - m2v);
            #pragma unroll
            for (int off = 1; off < 16; off <<= 1) {
                e1 += __shfl_xor(e1, off);
                e2 += __shfl_xor(e2, off);
            }
            float logp = (m1v + __logf(e1)) - (m2v + __logf(e2));
            sum += fminf(logp, 50.0f);
        }
        // next phase-1 writes GL only after barrier B1; HF stable; PL rewritten
        // behind next B2 -> no extra barrier needed here.
    }

    if (j < 256 && g3 == 0) out[blk*SPB + s3] = sum;
}

extern "C" void kernel_launch(void* const* d_in, const int* in_sizes, int n_in,
                              void* d_out, int out_size, void* d_ws, size_t ws_size,
                              hipStream_t stream) {
    const float* x     = (const float*)d_in[0];
    const float* z     = (const float*)d_in[1];
    const float* iseq  = (const float*)d_in[2];
    const float* pseq  = (const float*)d_in[3];
    const float* Wh0   = (const float*)d_in[4];
    const float* bh0   = (const float*)d_in[5];
    const float* Wc0   = (const float*)d_in[6];
    const float* bc0   = (const float*)d_in[7];
    const float* Wih   = (const float*)d_in[8];
    const float* Whh   = (const float*)d_in[9];
    const float* bih   = (const float*)d_in[10];
    const float* bhh   = (const float*)d_in[11];
    const float* Wpi   = (const float*)d_in[12];
    const float* bpi   = (const float*)d_in[13];
    const float* Wmu   = (const float*)d_in[14];
    const float* bmu   = (const float*)d_in[15];
    const float* Wls   = (const float*)d_in[16];
    const float* bls   = (const float*)d_in[17];
    const float* Wcorr = (const float*)d_in[18];
    const float* bcorr = (const float*)d_in[19];
    float* out = (float*)d_out;

    decoder_kernel<<<256, 512, 0, stream>>>(x, z, iseq, pseq, Wh0, bh0, Wc0, bc0,
                                            Wih, Whh, bih, bhh, Wpi, bpi, Wmu, bmu,
                                            Wls, bls, Wcorr, bcorr, out);
}